// Round 6
// baseline (467.237 us; speedup 1.0000x reference)
//
#include <hip/hip_runtime.h>
#include <math.h>

// Problem constants
#define B_   4096
#define N_   64
#define SS_  5
#define I_   7
#define H_   256
#define M1_  512
#define M2_  512
#define A_   81

typedef _Float16 f16;
typedef f16   f16x8 __attribute__((ext_vector_type(8)));
typedef float f32x4 __attribute__((ext_vector_type(4)));

__device__ __forceinline__ void fma4(float4& a, float s, const float4 w) {
  a.x = fmaf(s, w.x, a.x);
  a.y = fmaf(s, w.y, a.y);
  a.z = fmaf(s, w.z, a.z);
  a.w = fmaf(s, w.w, a.w);
}

__device__ __forceinline__ float4 relu4(float4 v) {
  v.x = fmaxf(v.x, 0.f); v.y = fmaxf(v.y, 0.f);
  v.z = fmaxf(v.z, 0.f); v.w = fmaxf(v.w, 0.f);
  return v;
}

__device__ __forceinline__ float sigm_(float x) {
  return __builtin_amdgcn_rcpf(1.f + __expf(-x));
}
__device__ __forceinline__ float tanh_(float x) {
  return 1.f - 2.f * __builtin_amdgcn_rcpf(__expf(2.f * x) + 1.f);
}

// ---------------------------------------------------------------------------
// Kernel 0: pack LSTM weights, single f16.
// Gate-col view: p = w*128 + g*32 + uu  (wave w in [0,8), gate g, unit
// u = w*32+uu); MFMA-tile view: p = w*128 + ct*16 + l15 (ct = g*2 + uu/16).
// Wpk[kt][p][k32]      kt 0..5 (register frags; global coalesced loads)
// Wpk_lds[k2][w][ct][l15][lg][j]  kt 6,7 lane-major (conflict-free LDS reads)
// Wxk[p][8]            x part (j<7 real, j=7 zero), broadcast reads
// bsum_p[p] = b_ih+b_hh.
// ---------------------------------------------------------------------------
__global__ void pack_weights(const float* __restrict__ W_ih,
                             const float* __restrict__ W_hh,
                             const float* __restrict__ b_ih,
                             const float* __restrict__ b_hh,
                             f16* __restrict__ Wpk,
                             f16* __restrict__ Wpk_lds,
                             f16* __restrict__ Wxk,
                             float* __restrict__ bsum_p) {
  const int idx = blockIdx.x * blockDim.x + threadIdx.x;
  if (idx < 6 * 1024 * 32) {               // register k-tiles 0..5
    const int k32 = idx & 31;
    const int p   = (idx >> 5) & 1023;
    const int kt  = idx >> 15;
    const int w   = p >> 7;
    const int r   = p & 127;
    const int g   = r >> 5;
    const int uu  = r & 31;
    const int row = g * H_ + w * 32 + uu;
    Wpk[idx] = (f16)W_hh[row * H_ + kt * 32 + k32];
  }
  if (idx < 65536) {                        // LDS k-tiles 6,7, lane-major
    const int j   = idx & 7;
    const int lg  = (idx >> 3) & 3;
    const int l15 = (idx >> 5) & 15;
    const int ct  = (idx >> 9) & 7;
    const int w   = (idx >> 12) & 7;
    const int k2  = idx >> 15;
    const int g   = ct >> 1;
    const int uu  = (ct & 1) * 16 + l15;
    const int row = g * H_ + w * 32 + uu;
    const int k   = (6 + k2) * 32 + lg * 8 + j;
    Wpk_lds[idx] = (f16)W_hh[row * H_ + k];
  }
  if (idx < 1024 * 8) {
    const int j = idx & 7;
    const int p = idx >> 3;
    const int w = p >> 7, r = p & 127, g = r >> 5, uu = r & 31;
    const int row = g * H_ + w * 32 + uu;
    Wxk[idx] = (j < I_) ? (f16)W_ih[row * I_ + j] : (f16)0.f;
  }
  if (idx < 1024) {
    const int w = idx >> 7, r = idx & 127, g = r >> 5, uu = r & 31;
    const int row = g * H_ + w * 32 + uu;
    bsum_p[idx] = b_ih[row] + b_hh[row];
  }
}

// ---------------------------------------------------------------------------
// Kernel 1: distance + stable descending rank-sort + gather.
// xbuf: f16 [t][B][7]; selfbuf: f32 [B][5].
// ---------------------------------------------------------------------------
__global__ void sort_gather(const float* __restrict__ state,
                            f16* __restrict__ xbuf,
                            float* __restrict__ selfbuf) {
  const int b = blockIdx.x;
  const int e = threadIdx.x;                 // 0..63, one wave
  const float* row = state + ((size_t)b * N_ + e) * 12;
  const float4* r4 = (const float4*)row;
  const float4 v0 = r4[0], v1 = r4[1], v2 = r4[2];
  float s[12];
  s[0]=v0.x; s[1]=v0.y; s[2]=v0.z;  s[3]=v0.w;
  s[4]=v1.x; s[5]=v1.y; s[6]=v1.z;  s[7]=v1.w;
  s[8]=v2.x; s[9]=v2.y; s[10]=v2.z; s[11]=v2.w;

  const float s5 = s[5], s6 = s[6];
  const float d = (s5 != 0.f && s6 != 0.f) ? sqrtf(s5 * s5 + s6 * s6) : INFINITY;

  __shared__ float dd[64];
  dd[e] = d;
  __syncthreads();

  int rank = 0;
  #pragma unroll
  for (int j = 0; j < 64; ++j) {
    const float dj = dd[j];
    rank += (dj > d || (dj == d && j < e)) ? 1 : 0;
  }

  f16* xo = xbuf + ((size_t)rank * B_ + b) * I_;
  #pragma unroll
  for (int f = 0; f < I_; ++f) xo[f] = (f16)s[SS_ + f];

  if (e == 0) {
    #pragma unroll
    for (int i = 0; i < SS_; ++i) selfbuf[b * SS_ + i] = s[i];
  }
}

// ---------------------------------------------------------------------------
// Kernel 2: MFMA LSTM, CU-resident weights. 256 blocks x 512 threads (8
// waves = 2/SIMD, 1 block/CU), 16 batches/block. waves_per_eu(2,2) pins the
// occupancy target so the allocator keeps kt 0..5 of W_hh in VGPRs (192).
// kt 6,7 + x-tile + bias in LDS (lane-major, conflict-free reads). h in LDS
// as A-frag slabs [kt][lg][b][8]. x prefetched one step ahead in a register.
// LDS: 131072 + 16384 + 8192 + 4096 + 256 = 160000 B.
// ---------------------------------------------------------------------------
__global__ __attribute__((amdgpu_flat_work_group_size(512, 512)))
           __attribute__((amdgpu_waves_per_eu(2, 2)))
void lstm_kernel(
    const f16* __restrict__ xbuf,      // [64][B][7]
    const f16* __restrict__ Wpk,       // [6][1024][32]
    const f16* __restrict__ Wpk_lds,   // [2][8][8][16][4][8]
    const f16* __restrict__ Wxk,       // [1024][8]
    const float* __restrict__ bsum_p,  // [1024]
    float* __restrict__ hnbuf) {       // [B][256] fp32
  const int tid = threadIdx.x;
  const int l   = tid & 63;
  const int w   = tid >> 6;             // wave 0..7
  const int l15 = l & 15;
  const int lg  = l >> 4;               // 0..3
  const int b0  = blockIdx.x << 4;      // 16 batches per block

  extern __shared__ char smem[];
  f16*   Bl_s = (f16*)smem;                  // [2][8][8][16][4][8]  131072 B
  f16*   Bx_s = (f16*)(smem + 131072);       // [1024][8]             16384 B
  f16*   h_s  = (f16*)(smem + 147456);       // [8][4][16][8]          8192 B
  float* bs_s = (float*)(smem + 155648);     // [1024]                 4096 B
  f16*   x_s  = (f16*)(smem + 159744);       // [16][8]                 256 B

  // x staging index (padded rows of 8)
  const int xb = tid / I_;              // batch 0..15 (tid<112)
  const int xj = tid - xb * I_;
  const int xsl = xb * 8 + xj;

  // --- one-time staging (coalesced linear copies) ---
  {
    const f16x8* src = (const f16x8*)Wpk_lds;
    f16x8* dst = (f16x8*)Bl_s;
    for (int i = tid; i < 8192; i += 512) dst[i] = src[i];
    const f16x8* sx = (const f16x8*)Wxk;
    f16x8* dx = (f16x8*)Bx_s;
    for (int i = tid; i < 1024; i += 512) dx[i] = sx[i];
    for (int i = tid; i < 1024; i += 512) bs_s[i] = bsum_p[i];
    f16x8* hz = (f16x8*)h_s;
    for (int i = tid; i < 512; i += 512)
      hz[i] = (f16x8){(f16)0.f,(f16)0.f,(f16)0.f,(f16)0.f,
                      (f16)0.f,(f16)0.f,(f16)0.f,(f16)0.f};
    if (tid < 16 * I_) x_s[xsl] = xbuf[b0 * I_ + tid];   // x for t=0
  }

  // --- persistent B fragments, kt 0..5 (192 VGPRs) ---
  const int gbase = w * 4096 + l15 * 32 + lg * 8;   // f16 units
  f16x8 B[6][8];
  #pragma unroll
  for (int kt = 0; kt < 6; ++kt) {
    #pragma unroll
    for (int ct = 0; ct < 8; ++ct)
      B[kt][ct] = *(const f16x8*)(Wpk + kt * 32768 + ct * 512 + gbase);
  }

  const int lbase = (l15 * 4 + lg) * 8;   // lane offset within LDS B subtile
  const int hrd   = lg * 128 + l15 * 8;   // h A-frag read base (+kt*512)

  float c_[2][4];
  #pragma unroll
  for (int uh = 0; uh < 2; ++uh)
    #pragma unroll
    for (int q = 0; q < 4; ++q) c_[uh][q] = 0.f;

  __syncthreads();   // staging visible

  #pragma unroll 1
  for (int t = 0; t < 64; ++t) {
    // prefetch x for step t+1 (consumed after the mid-step barrier)
    f16 xn = (f16)0.f;
    {
      const int tn = (t < 63) ? t + 1 : 63;
      if (tid < 16 * I_) xn = xbuf[(size_t)tn * (B_ * I_) + b0 * I_ + tid];
    }

    // anti-sink: keep the weight fragments register-resident
    #pragma unroll
    for (int kt = 0; kt < 6; ++kt)
      #pragma unroll
      for (int ct = 0; ct < 8; ++ct)
        asm volatile("" : "+v"(B[kt][ct]));

    // x A-fragment: row=batch=l15, k=lg*8+j valid only for lg==0, j<7
    f16x8 ax = {(f16)0.f,(f16)0.f,(f16)0.f,(f16)0.f,
                (f16)0.f,(f16)0.f,(f16)0.f,(f16)0.f};
    if (lg == 0) {
      #pragma unroll
      for (int j = 0; j < I_; ++j) ax[j] = x_s[l15 * 8 + j];
    }

    f32x4 acc[8];
    #pragma unroll
    for (int ct = 0; ct < 8; ++ct) acc[ct] = (f32x4){0.f, 0.f, 0.f, 0.f};

    // kt 0..5: B from registers
    #pragma unroll
    for (int kt = 0; kt < 6; ++kt) {
      const f16x8 Af = *(const f16x8*)&h_s[kt * 512 + hrd];
      #pragma unroll
      for (int ct = 0; ct < 8; ++ct)
        acc[ct] = __builtin_amdgcn_mfma_f32_16x16x32_f16(Af, B[kt][ct], acc[ct], 0, 0, 0);
    }
    // kt 6,7: B from LDS (lane-major subtiles, conflict-free)
    #pragma unroll
    for (int k2 = 0; k2 < 2; ++k2) {
      const f16x8 Af = *(const f16x8*)&h_s[(6 + k2) * 512 + hrd];
      #pragma unroll
      for (int ct = 0; ct < 8; ++ct) {
        const f16x8 Bv = *(const f16x8*)(Bl_s + k2 * 32768 + (w * 8 + ct) * 512 + lbase);
        acc[ct] = __builtin_amdgcn_mfma_f32_16x16x32_f16(Af, Bv, acc[ct], 0, 0, 0);
      }
    }
    // x tile: B from LDS (lg-broadcast)
    #pragma unroll
    for (int ct = 0; ct < 8; ++ct) {
      const f16x8 Bv = *(const f16x8*)(Bx_s + (w * 128 + ct * 16 + l15) * 8);
      acc[ct] = __builtin_amdgcn_mfma_f32_16x16x32_f16(ax, Bv, acc[ct], 0, 0, 0);
    }
    __syncthreads();   // all h_s / x_s reads complete before overwrite

    // epilogue: lane owns units u = w*32 + uh*16 + l15 for batches lg*4+q
    #pragma unroll
    for (int uh = 0; uh < 2; ++uh) {
      const int u  = w * 32 + uh * 16 + l15;
      const int wb = w * 512 + (uh * 2 + (l15 >> 3)) * 128 + (l15 & 7);
      const float bi_ = bs_s[w * 128 + 0 * 32 + uh * 16 + l15];
      const float bf_ = bs_s[w * 128 + 1 * 32 + uh * 16 + l15];
      const float bg_ = bs_s[w * 128 + 2 * 32 + uh * 16 + l15];
      const float bo_ = bs_s[w * 128 + 3 * 32 + uh * 16 + l15];
      #pragma unroll
      for (int q = 0; q < 4; ++q) {
        const int b = lg * 4 + q;
        const float gi = acc[0 + uh][q] + bi_;
        const float gf = acc[2 + uh][q] + bf_;
        const float gg = acc[4 + uh][q] + bg_;
        const float go = acc[6 + uh][q] + bo_;
        const float cn = sigm_(gf) * c_[uh][q] + sigm_(gi) * tanh_(gg);
        c_[uh][q] = cn;
        const float h = sigm_(go) * tanh_(cn);
        h_s[wb + b * 8] = (f16)h;
        if (t == 63) hnbuf[(size_t)(b0 + b) * H_ + u] = h;
      }
    }
    if (tid < 16 * I_) x_s[xsl] = xn;   // publish x for step t+1
    __syncthreads();   // h_s / x_s writes visible for next step
  }
}

// ---------------------------------------------------------------------------
// Kernel 3: fused MLP head. 256 blocks x 512 threads, 16 batches per block.
// Dynamic LDS: a0 16x264 + a1 16x512 + a2 16x512 = 82432 B.
// ---------------------------------------------------------------------------
__global__ __launch_bounds__(512) void mlp_kernel(
    const float* __restrict__ selfb, const float* __restrict__ hnbuf,
    const float* __restrict__ W1, const float* __restrict__ b1,
    const float* __restrict__ W2, const float* __restrict__ b2,
    const float* __restrict__ Wv, const float* __restrict__ bv,
    float* __restrict__ out) {
  const int tid = threadIdx.x;
  const int b0  = blockIdx.x << 4;      // 16 batches per block
  const int tb  = tid >> 7;             // 0..3 (batch group)
  const int tn  = tid & 127;            // float4 column group (N=512 -> 128)

  extern __shared__ char smem[];
  float* a0 = (float*)smem;                    // [16][264]
  float* a1 = (float*)(smem + 16896);          // [16][512]
  float* a2 = (float*)(smem + 16896 + 32768);  // [16][512]

  for (int i = tid; i < 16 * SS_; i += 512)
    a0[(i / SS_) * 264 + (i % SS_)] = selfb[b0 * SS_ + i];
  for (int i = tid; i < 16 * H_; i += 512)
    a0[(i >> 8) * 264 + SS_ + (i & 255)] = hnbuf[((size_t)b0 << 8) + i];
  __syncthreads();

  float4 acc[4];

  { // layer 1: K=261, N=512
    const float4* W14 = (const float4*)W1;
    const float4 bb = ((const float4*)b1)[tn];
    #pragma unroll
    for (int q = 0; q < 4; ++q) acc[q] = bb;
    for (int k = 0; k < SS_ + H_; ++k) {
      const float4 w0 = W14[k * 128 + tn];
      #pragma unroll
      for (int q = 0; q < 4; ++q)
        fma4(acc[q], a0[(tb * 4 + q) * 264 + k], w0);
    }
    #pragma unroll
    for (int q = 0; q < 4; ++q)
      *(float4*)&a1[(tb * 4 + q) * 512 + tn * 4] = relu4(acc[q]);
  }
  __syncthreads();

  { // layer 2: K=512, N=512
    const float4* W24 = (const float4*)W2;
    const float4 bb = ((const float4*)b2)[tn];
    #pragma unroll
    for (int q = 0; q < 4; ++q) acc[q] = bb;
    for (int k = 0; k < M1_; ++k) {
      const float4 w0 = W24[k * 128 + tn];
      #pragma unroll
      for (int q = 0; q < 4; ++q)
        fma4(acc[q], a1[(tb * 4 + q) * 512 + k], w0);
    }
    #pragma unroll
    for (int q = 0; q < 4; ++q)
      *(float4*)&a2[(tb * 4 + q) * 512 + tn * 4] = relu4(acc[q]);
  }
  __syncthreads();

  // layer 3: K=512, N=81
  for (int idx = tid; idx < 16 * A_; idx += 512) {
    const int bi = idx / A_;
    const int n  = idx - bi * A_;
    float sum = bv[n];
    for (int k = 0; k < M2_; ++k)
      sum = fmaf(a2[bi * 512 + k], Wv[k * A_ + n], sum);
    out[(size_t)(b0 + bi) * A_ + n] = sum;
  }
}

// ---------------------------------------------------------------------------
extern "C" void kernel_launch(void* const* d_in, const int* in_sizes, int n_in,
                              void* d_out, int out_size, void* d_ws, size_t ws_size,
                              hipStream_t stream) {
  const float* state = (const float*)d_in[0];
  const float* W_ih  = (const float*)d_in[1];
  const float* W_hh  = (const float*)d_in[2];
  const float* b_ih  = (const float*)d_in[3];
  const float* b_hh  = (const float*)d_in[4];
  const float* W1    = (const float*)d_in[5];
  const float* b1    = (const float*)d_in[6];
  const float* W2    = (const float*)d_in[7];
  const float* b2    = (const float*)d_in[8];
  const float* Wv    = (const float*)d_in[9];
  const float* bv    = (const float*)d_in[10];
  float* out = (float*)d_out;

  // workspace layout (bytes, 16B-aligned); total ~8.6 MB
  char* ws = (char*)d_ws;
  f16*   Wpk     = (f16*)(ws);                 // 6*1024*32 f16 = 393216 B
  f16*   Wpk_lds = (f16*)(ws + 393216);        // 65536 f16     = 131072 B
  f16*   Wxk     = (f16*)(ws + 524288);        // 1024*8 f16    = 16384 B
  float* bsum_p  = (float*)(ws + 540672);      // 1024 f32      = 4096 B
  f16*   xbuf    = (f16*)(ws + 544768);        // 64*4096*7 f16 = 3670016 B
  float* selfb   = (float*)(ws + 4214784);     // 4096*5 f32    = 81920 B
  float* hnbuf   = (float*)(ws + 4296704);     // 4096*256 f32  = 4194304 B

  pack_weights<<<dim3(768), dim3(256), 0, stream>>>(W_ih, W_hh, b_ih, b_hh,
                                                    Wpk, Wpk_lds, Wxk, bsum_p);
  sort_gather<<<dim3(B_), dim3(64), 0, stream>>>(state, xbuf, selfb);
  lstm_kernel<<<dim3(B_ / 16), dim3(512), 160000, stream>>>(xbuf, Wpk, Wpk_lds,
                                                            Wxk, bsum_p, hnbuf);
  mlp_kernel<<<dim3(B_ / 16), dim3(512), 82432, stream>>>(selfb, hnbuf, W1, b1,
                                                          W2, b2, Wv, bv, out);
}

// Round 8
// 386.401 us; speedup vs baseline: 1.2092x; 1.2092x over previous
//
#include <hip/hip_runtime.h>
#include <math.h>

// Problem constants
#define B_   4096
#define N_   64
#define SS_  5
#define I_   7
#define H_   256
#define M1_  512
#define M2_  512
#define A_   81

typedef _Float16 f16;
typedef f16   f16x8 __attribute__((ext_vector_type(8)));
typedef float f32x4 __attribute__((ext_vector_type(4)));

__device__ __forceinline__ void fma4(float4& a, float s, const float4 w) {
  a.x = fmaf(s, w.x, a.x);
  a.y = fmaf(s, w.y, a.y);
  a.z = fmaf(s, w.z, a.z);
  a.w = fmaf(s, w.w, a.w);
}

__device__ __forceinline__ float4 relu4(float4 v) {
  v.x = fmaxf(v.x, 0.f); v.y = fmaxf(v.y, 0.f);
  v.z = fmaxf(v.z, 0.f); v.w = fmaxf(v.w, 0.f);
  return v;
}

__device__ __forceinline__ float sigm_(float x) {
  return __builtin_amdgcn_rcpf(1.f + __expf(-x));
}
__device__ __forceinline__ float tanh_(float x) {
  return 1.f - 2.f * __builtin_amdgcn_rcpf(__expf(2.f * x) + 1.f);
}

// ---------------------------------------------------------------------------
// Kernel 0: pack LSTM weights, single f16.
// Gate-col view: p = w*128 + g*32 + uu (wave w in [0,8), gate g, unit
// u = w*32+uu); MFMA-tile view: p = w*128 + ct*16 + l15 (ct = g*2 + uu/16).
// Wpk[kt][p][k32]               kt 0..4  (register fragments)
// Wpk_lds[k2][w][ct][l15][lg][j] kt 5,6  lane-major (conflict-free LDS)
// Wst[p][k32]                   kt 7     (streamed from L2 each step)
// Wxk[p][8]                     x part (j<7 real, j=7 zero)
// bsum_p[p] = b_ih + b_hh
// ---------------------------------------------------------------------------
__global__ void pack_weights(const float* __restrict__ W_ih,
                             const float* __restrict__ W_hh,
                             const float* __restrict__ b_ih,
                             const float* __restrict__ b_hh,
                             f16* __restrict__ Wpk,
                             f16* __restrict__ Wpk_lds,
                             f16* __restrict__ Wst,
                             f16* __restrict__ Wxk,
                             float* __restrict__ bsum_p) {
  const int idx = blockIdx.x * blockDim.x + threadIdx.x;
  if (idx < 5 * 1024 * 32) {               // register k-tiles 0..4
    const int k32 = idx & 31;
    const int p   = (idx >> 5) & 1023;
    const int kt  = idx >> 15;
    const int w   = p >> 7;
    const int r   = p & 127;
    const int g   = r >> 5;
    const int uu  = r & 31;
    const int row = g * H_ + w * 32 + uu;
    Wpk[idx] = (f16)W_hh[row * H_ + kt * 32 + k32];
  }
  if (idx < 65536) {                        // LDS k-tiles 5,6, lane-major
    const int j   = idx & 7;
    const int lg  = (idx >> 3) & 3;
    const int l15 = (idx >> 5) & 15;
    const int ct  = (idx >> 9) & 7;
    const int w   = (idx >> 12) & 7;
    const int k2  = idx >> 15;
    const int g   = ct >> 1;
    const int uu  = (ct & 1) * 16 + l15;
    const int row = g * H_ + w * 32 + uu;
    const int k   = (5 + k2) * 32 + lg * 8 + j;
    Wpk_lds[idx] = (f16)W_hh[row * H_ + k];
  }
  if (idx < 32768) {                        // streamed k-tile 7
    const int k32 = idx & 31;
    const int p   = idx >> 5;
    const int w = p >> 7, r = p & 127, g = r >> 5, uu = r & 31;
    const int row = g * H_ + w * 32 + uu;
    Wst[idx] = (f16)W_hh[row * H_ + 224 + k32];
  }
  if (idx < 1024 * 8) {
    const int j = idx & 7;
    const int p = idx >> 3;
    const int w = p >> 7, r = p & 127, g = r >> 5, uu = r & 31;
    const int row = g * H_ + w * 32 + uu;
    Wxk[idx] = (j < I_) ? (f16)W_ih[row * I_ + j] : (f16)0.f;
  }
  if (idx < 1024) {
    const int w = idx >> 7, r = idx & 127, g = r >> 5, uu = r & 31;
    const int row = g * H_ + w * 32 + uu;
    bsum_p[idx] = b_ih[row] + b_hh[row];
  }
}

// ---------------------------------------------------------------------------
// Kernel 1: distance + stable descending rank-sort + gather.
// xbuf: f16 [t][B][7]; selfbuf: f32 [B][5].
// ---------------------------------------------------------------------------
__global__ void sort_gather(const float* __restrict__ state,
                            f16* __restrict__ xbuf,
                            float* __restrict__ selfbuf) {
  const int b = blockIdx.x;
  const int e = threadIdx.x;                 // 0..63, one wave
  const float* row = state + ((size_t)b * N_ + e) * 12;
  const float4* r4 = (const float4*)row;
  const float4 v0 = r4[0], v1 = r4[1], v2 = r4[2];
  float s[12];
  s[0]=v0.x; s[1]=v0.y; s[2]=v0.z;  s[3]=v0.w;
  s[4]=v1.x; s[5]=v1.y; s[6]=v1.z;  s[7]=v1.w;
  s[8]=v2.x; s[9]=v2.y; s[10]=v2.z; s[11]=v2.w;

  const float s5 = s[5], s6 = s[6];
  const float d = (s5 != 0.f && s6 != 0.f) ? sqrtf(s5 * s5 + s6 * s6) : INFINITY;

  __shared__ float dd[64];
  dd[e] = d;
  __syncthreads();

  int rank = 0;
  #pragma unroll
  for (int j = 0; j < 64; ++j) {
    const float dj = dd[j];
    rank += (dj > d || (dj == d && j < e)) ? 1 : 0;
  }

  f16* xo = xbuf + ((size_t)rank * B_ + b) * I_;
  #pragma unroll
  for (int f = 0; f < I_; ++f) xo[f] = (f16)s[SS_ + f];

  if (e == 0) {
    #pragma unroll
    for (int i = 0; i < SS_; ++i) selfbuf[b * SS_ + i] = s[i];
  }
}

// ---------------------------------------------------------------------------
// Kernel 2: MFMA LSTM. 256 blocks x 512 threads (8 waves = 2/SIMD,
// 1 block/CU), 16 batches/block. Wave w owns packed cols [128w,128w+128):
// kt 0..4 of W_hh in VGPRs (160, asm-pinned), kt 5,6 + x-tile + bias in
// LDS, kt 7 streamed from L2 each step (transient 32 regs). ALL
// loop-invariant B/bias reads are laundered through an opaque z=0 so LICM
// cannot hoist them into resident registers (the R5/R6 failure mode).
// LDS: 131072 + 16384 + 8192 + 4096 + 256 = 160000 B.
// ---------------------------------------------------------------------------
__global__ __attribute__((amdgpu_flat_work_group_size(512, 512)))
           __attribute__((amdgpu_waves_per_eu(2, 2)))
void lstm_kernel(
    const f16* __restrict__ xbuf,      // [64][B][7]
    const f16* __restrict__ Wpk,       // [5][1024][32]
    const f16* __restrict__ Wpk_lds,   // [2][8][8][16][4][8]
    const f16* __restrict__ Wst,       // [1024][32]
    const f16* __restrict__ Wxk,       // [1024][8]
    const float* __restrict__ bsum_p,  // [1024]
    float* __restrict__ hnbuf) {       // [B][256] fp32
  const int tid = threadIdx.x;
  const int l   = tid & 63;
  const int w   = tid >> 6;             // wave 0..7
  const int l15 = l & 15;
  const int lg  = l >> 4;               // 0..3
  const int b0  = blockIdx.x << 4;      // 16 batches per block

  extern __shared__ char smem[];
  f16*   Bl_s = (f16*)smem;                  // [2][8][8][16][4][8]  131072 B
  f16*   Bx_s = (f16*)(smem + 131072);       // [1024][8]             16384 B
  f16*   h_s  = (f16*)(smem + 147456);       // [8][4][16][8]          8192 B
  float* bs_s = (float*)(smem + 155648);     // [1024]                 4096 B
  f16*   x_s  = (f16*)(smem + 159744);       // [16][8]                 256 B

  // x staging index (padded rows of 8)
  const int xb = tid / I_;              // batch 0..15 (tid<112)
  const int xj = tid - xb * I_;
  const int xsl = xb * 8 + xj;

  // --- one-time staging (coalesced linear copies) ---
  {
    const f16x8* src = (const f16x8*)Wpk_lds;
    f16x8* dst = (f16x8*)Bl_s;
    for (int i = tid; i < 8192; i += 512) dst[i] = src[i];
    const f16x8* sx = (const f16x8*)Wxk;
    f16x8* dx = (f16x8*)Bx_s;
    for (int i = tid; i < 1024; i += 512) dx[i] = sx[i];
    for (int i = tid; i < 1024; i += 512) bs_s[i] = bsum_p[i];
    f16x8* hz = (f16x8*)h_s;
    for (int i = tid; i < 512; i += 512)
      hz[i] = (f16x8){(f16)0.f,(f16)0.f,(f16)0.f,(f16)0.f,
                      (f16)0.f,(f16)0.f,(f16)0.f,(f16)0.f};
    if (tid < 16 * I_) x_s[xsl] = xbuf[b0 * I_ + tid];   // x for t=0
  }

  // --- persistent B fragments, kt 0..4 (160 VGPRs) ---
  const int gbase = w * 4096 + l15 * 32 + lg * 8;   // f16 units
  f16x8 B[5][8];
  #pragma unroll
  for (int kt = 0; kt < 5; ++kt) {
    #pragma unroll
    for (int ct = 0; ct < 8; ++ct)
      B[kt][ct] = *(const f16x8*)(Wpk + kt * 32768 + ct * 512 + gbase);
  }

  const int lbase = (l15 * 4 + lg) * 8;   // lane offset within LDS B subtile
  const int hrd   = lg * 128 + l15 * 8;   // h A-frag read base (+kt*512)

  float c_[2][4];
  #pragma unroll
  for (int uh = 0; uh < 2; ++uh)
    #pragma unroll
    for (int q = 0; q < 4; ++q) c_[uh][q] = 0.f;

  __syncthreads();   // staging visible

  #pragma unroll 1
  for (int t = 0; t < 64; ++t) {
    // opaque zero: defeats LICM on all loop-invariant reads below
    int z = 0;
    asm volatile("" : "+v"(z));

    // prefetch x for step t+1 (consumed after the mid-step barrier)
    f16 xn = (f16)0.f;
    {
      const int tn = (t < 63) ? t + 1 : 63;
      if (tid < 16 * I_) xn = xbuf[(size_t)tn * (B_ * I_) + b0 * I_ + tid];
    }

    // anti-sink: keep the 160 weight regs resident
    #pragma unroll
    for (int kt = 0; kt < 5; ++kt)
      #pragma unroll
      for (int ct = 0; ct < 8; ++ct)
        asm volatile("" : "+v"(B[kt][ct]));

    // x A-fragment: row=batch=l15, k=lg*8+j valid only for lg==0, j<7
    f16x8 ax = {(f16)0.f,(f16)0.f,(f16)0.f,(f16)0.f,
                (f16)0.f,(f16)0.f,(f16)0.f,(f16)0.f};
    if (lg == 0) {
      #pragma unroll
      for (int j = 0; j < I_; ++j) ax[j] = x_s[l15 * 8 + j];
    }

    f32x4 acc[8];
    #pragma unroll
    for (int ct = 0; ct < 8; ++ct) acc[ct] = (f32x4){0.f, 0.f, 0.f, 0.f};

    // kt 0..4: B from registers
    #pragma unroll
    for (int kt = 0; kt < 5; ++kt) {
      const f16x8 Af = *(const f16x8*)&h_s[kt * 512 + hrd];
      #pragma unroll
      for (int ct = 0; ct < 8; ++ct)
        acc[ct] = __builtin_amdgcn_mfma_f32_16x16x32_f16(Af, B[kt][ct], acc[ct], 0, 0, 0);
    }
    // kt 5,6: B from LDS (lane-major subtiles, conflict-free), laundered
    #pragma unroll
    for (int k2 = 0; k2 < 2; ++k2) {
      const f16x8 Af = *(const f16x8*)&h_s[(5 + k2) * 512 + hrd];
      #pragma unroll
      for (int ct = 0; ct < 8; ++ct) {
        const f16x8 Bv = *(const f16x8*)(Bl_s + k2 * 32768 + (w * 8 + ct) * 512 + lbase + z);
        acc[ct] = __builtin_amdgcn_mfma_f32_16x16x32_f16(Af, Bv, acc[ct], 0, 0, 0);
      }
    }
    // kt 7: B streamed from L2 (transient regs, loads just before use)
    {
      const f16x8 Af = *(const f16x8*)&h_s[7 * 512 + hrd];
      const f16* ps = Wst + gbase + z;
      #pragma unroll
      for (int ct = 0; ct < 8; ++ct) {
        const f16x8 Bv = *(const f16x8*)(ps + ct * 512);
        acc[ct] = __builtin_amdgcn_mfma_f32_16x16x32_f16(Af, Bv, acc[ct], 0, 0, 0);
      }
    }
    // x tile: B from LDS, laundered
    #pragma unroll
    for (int ct = 0; ct < 8; ++ct) {
      const f16x8 Bv = *(const f16x8*)(Bx_s + (w * 128 + ct * 16 + l15) * 8 + z);
      acc[ct] = __builtin_amdgcn_mfma_f32_16x16x32_f16(ax, Bv, acc[ct], 0, 0, 0);
    }
    __syncthreads();   // all h_s / x_s reads complete before overwrite

    // epilogue: lane owns units u = w*32 + uh*16 + l15 for batches lg*4+q
    #pragma unroll
    for (int uh = 0; uh < 2; ++uh) {
      const int u  = w * 32 + uh * 16 + l15;
      const int wb = w * 512 + (uh * 2 + (l15 >> 3)) * 128 + (l15 & 7);
      const float bi_ = bs_s[w * 128 + 0 * 32 + uh * 16 + l15 + z];
      const float bf_ = bs_s[w * 128 + 1 * 32 + uh * 16 + l15 + z];
      const float bg_ = bs_s[w * 128 + 2 * 32 + uh * 16 + l15 + z];
      const float bo_ = bs_s[w * 128 + 3 * 32 + uh * 16 + l15 + z];
      #pragma unroll
      for (int q = 0; q < 4; ++q) {
        const int b = lg * 4 + q;
        const float gi = acc[0 + uh][q] + bi_;
        const float gf = acc[2 + uh][q] + bf_;
        const float gg = acc[4 + uh][q] + bg_;
        const float go = acc[6 + uh][q] + bo_;
        const float cn = sigm_(gf) * c_[uh][q] + sigm_(gi) * tanh_(gg);
        c_[uh][q] = cn;
        const float h = sigm_(go) * tanh_(cn);
        h_s[wb + b * 8] = (f16)h;
        if (t == 63) hnbuf[(size_t)(b0 + b) * H_ + u] = h;
      }
    }
    if (tid < 16 * I_) x_s[xsl] = xn;   // publish x for step t+1
    __syncthreads();   // h_s / x_s writes visible for next step
  }
}

// ---------------------------------------------------------------------------
// Kernel 3: fused MLP head. 256 blocks x 512 threads, 16 batches per block.
// Dynamic LDS: a0 16x264 + a1 16x512 + a2 16x512 = 82432 B.
// ---------------------------------------------------------------------------
__global__ __launch_bounds__(512) void mlp_kernel(
    const float* __restrict__ selfb, const float* __restrict__ hnbuf,
    const float* __restrict__ W1, const float* __restrict__ b1,
    const float* __restrict__ W2, const float* __restrict__ b2,
    const float* __restrict__ Wv, const float* __restrict__ bv,
    float* __restrict__ out) {
  const int tid = threadIdx.x;
  const int b0  = blockIdx.x << 4;      // 16 batches per block
  const int tb  = tid >> 7;             // 0..3 (batch group)
  const int tn  = tid & 127;            // float4 column group (N=512 -> 128)

  extern __shared__ char smem[];
  float* a0 = (float*)smem;                    // [16][264]
  float* a1 = (float*)(smem + 16896);          // [16][512]
  float* a2 = (float*)(smem + 16896 + 32768);  // [16][512]

  for (int i = tid; i < 16 * SS_; i += 512)
    a0[(i / SS_) * 264 + (i % SS_)] = selfb[b0 * SS_ + i];
  for (int i = tid; i < 16 * H_; i += 512)
    a0[(i >> 8) * 264 + SS_ + (i & 255)] = hnbuf[((size_t)b0 << 8) + i];
  __syncthreads();

  float4 acc[4];

  { // layer 1: K=261, N=512
    const float4* W14 = (const float4*)W1;
    const float4 bb = ((const float4*)b1)[tn];
    #pragma unroll
    for (int q = 0; q < 4; ++q) acc[q] = bb;
    for (int k = 0; k < SS_ + H_; ++k) {
      const float4 w0 = W14[k * 128 + tn];
      #pragma unroll
      for (int q = 0; q < 4; ++q)
        fma4(acc[q], a0[(tb * 4 + q) * 264 + k], w0);
    }
    #pragma unroll
    for (int q = 0; q < 4; ++q)
      *(float4*)&a1[(tb * 4 + q) * 512 + tn * 4] = relu4(acc[q]);
  }
  __syncthreads();

  { // layer 2: K=512, N=512
    const float4* W24 = (const float4*)W2;
    const float4 bb = ((const float4*)b2)[tn];
    #pragma unroll
    for (int q = 0; q < 4; ++q) acc[q] = bb;
    for (int k = 0; k < M1_; ++k) {
      const float4 w0 = W24[k * 128 + tn];
      #pragma unroll
      for (int q = 0; q < 4; ++q)
        fma4(acc[q], a1[(tb * 4 + q) * 512 + k], w0);
    }
    #pragma unroll
    for (int q = 0; q < 4; ++q)
      *(float4*)&a2[(tb * 4 + q) * 512 + tn * 4] = relu4(acc[q]);
  }
  __syncthreads();

  // layer 3: K=512, N=81
  for (int idx = tid; idx < 16 * A_; idx += 512) {
    const int bi = idx / A_;
    const int n  = idx - bi * A_;
    float sum = bv[n];
    for (int k = 0; k < M2_; ++k)
      sum = fmaf(a2[bi * 512 + k], Wv[k * A_ + n], sum);
    out[(size_t)(b0 + bi) * A_ + n] = sum;
  }
}

// ---------------------------------------------------------------------------
extern "C" void kernel_launch(void* const* d_in, const int* in_sizes, int n_in,
                              void* d_out, int out_size, void* d_ws, size_t ws_size,
                              hipStream_t stream) {
  const float* state = (const float*)d_in[0];
  const float* W_ih  = (const float*)d_in[1];
  const float* W_hh  = (const float*)d_in[2];
  const float* b_ih  = (const float*)d_in[3];
  const float* b_hh  = (const float*)d_in[4];
  const float* W1    = (const float*)d_in[5];
  const float* b1    = (const float*)d_in[6];
  const float* W2    = (const float*)d_in[7];
  const float* b2    = (const float*)d_in[8];
  const float* Wv    = (const float*)d_in[9];
  const float* bv    = (const float*)d_in[10];
  float* out = (float*)d_out;

  // workspace layout (bytes, 16B-aligned); total ~8.5 MB
  char* ws = (char*)d_ws;
  f16*   Wpk     = (f16*)(ws);                 // 5*1024*32 f16 = 327680 B
  f16*   Wpk_lds = (f16*)(ws + 327680);        // 65536 f16     = 131072 B
  f16*   Wst     = (f16*)(ws + 458752);        // 1024*32 f16   = 65536 B
  f16*   Wxk     = (f16*)(ws + 524288);        // 1024*8 f16    = 16384 B
  float* bsum_p  = (float*)(ws + 540672);      // 1024 f32      = 4096 B
  f16*   xbuf    = (f16*)(ws + 544768);        // 64*4096*7 f16 = 3670016 B
  float* selfb   = (float*)(ws + 4214784);     // 4096*5 f32    = 81920 B
  float* hnbuf   = (float*)(ws + 4296704);     // 4096*256 f32  = 4194304 B

  pack_weights<<<dim3(640), dim3(256), 0, stream>>>(W_ih, W_hh, b_ih, b_hh,
                                                    Wpk, Wpk_lds, Wst, Wxk,
                                                    bsum_p);
  sort_gather<<<dim3(B_), dim3(64), 0, stream>>>(state, xbuf, selfb);
  lstm_kernel<<<dim3(B_ / 16), dim3(512), 160000, stream>>>(xbuf, Wpk, Wpk_lds,
                                                            Wst, Wxk, bsum_p,
                                                            hnbuf);
  mlp_kernel<<<dim3(B_ / 16), dim3(512), 82432, stream>>>(selfb, hnbuf, W1, b1,
                                                          W2, b2, Wv, bv, out);
}

// Round 9
// 336.117 us; speedup vs baseline: 1.3901x; 1.1496x over previous
//
#include <hip/hip_runtime.h>
#include <math.h>

// Problem constants
#define B_   4096
#define N_   64
#define SS_  5
#define I_   7
#define H_   256
#define M1_  512
#define M2_  512
#define A_   81

typedef _Float16 f16;
typedef f16   f16x8 __attribute__((ext_vector_type(8)));
typedef float f32x4 __attribute__((ext_vector_type(4)));
typedef int   i32x4 __attribute__((ext_vector_type(4)));

__device__ __forceinline__ void fma4(float4& a, float s, const float4 w) {
  a.x = fmaf(s, w.x, a.x);
  a.y = fmaf(s, w.y, a.y);
  a.z = fmaf(s, w.z, a.z);
  a.w = fmaf(s, w.w, a.w);
}

__device__ __forceinline__ float4 relu4(float4 v) {
  v.x = fmaxf(v.x, 0.f); v.y = fmaxf(v.y, 0.f);
  v.z = fmaxf(v.z, 0.f); v.w = fmaxf(v.w, 0.f);
  return v;
}

__device__ __forceinline__ float sigm_(float x) {
  return __builtin_amdgcn_rcpf(1.f + __expf(-x));
}
__device__ __forceinline__ float tanh_(float x) {
  return 1.f - 2.f * __builtin_amdgcn_rcpf(__expf(2.f * x) + 1.f);
}

// ---------------------------------------------------------------------------
// Kernel 0: pack weights. One WAVE per packed column p (1024 waves).
// p = w*128 + ct*16 + l15 view; gate decomposition p = w*128 + g*32 + uu.
// Wq[kt][p][k32] i8 with per-column scale mx = max|col|:
//   Wq = round(W * 127/mx)            (W ≈ Wq·mx/127)
// scd[p]    = mx/127^2                (i32 -> gate dequant, × sh)
// invq127[p]= 127^2/mx                (f32 -> i32 fold, × 1/sh)
// bsum_p[p] = b_ih+b_hh;  Wxk[p][8] f16 x-weights (j<7 real, j=7 zero).
// ---------------------------------------------------------------------------
__global__ __launch_bounds__(1024) void pack_weights(
    const float* __restrict__ W_ih,
    const float* __restrict__ W_hh,
    const float* __restrict__ b_ih,
    const float* __restrict__ b_hh,
    signed char* __restrict__ Wq,
    f16* __restrict__ Wxk,
    float* __restrict__ bsum_p,
    float* __restrict__ scd,
    float* __restrict__ invq127) {
  const int gtid = blockIdx.x * 1024 + threadIdx.x;
  const int p    = gtid >> 6;           // one wave per column
  const int lane = gtid & 63;
  const int w = p >> 7, r = p & 127, g = r >> 5, uu = r & 31;
  const int row = g * H_ + w * 32 + uu;

  // lane owns k = lane*4 .. lane*4+3 (coalesced float4)
  const float4 v4 = *(const float4*)(W_hh + row * H_ + lane * 4);
  float mx = fmaxf(fmaxf(fabsf(v4.x), fabsf(v4.y)),
                   fmaxf(fabsf(v4.z), fabsf(v4.w)));
  #pragma unroll
  for (int off = 32; off; off >>= 1)
    mx = fmaxf(mx, __shfl_xor(mx, off));
  mx = fmaxf(mx, 1e-12f);
  const float is = 127.f / mx;

  // quantize own 4 values, pack to one dword
  int b0i = (int)rintf(v4.x * is), b1i = (int)rintf(v4.y * is);
  int b2i = (int)rintf(v4.z * is), b3i = (int)rintf(v4.w * is);
  b0i = max(-127, min(127, b0i)); b1i = max(-127, min(127, b1i));
  b2i = max(-127, min(127, b2i)); b3i = max(-127, min(127, b3i));
  const unsigned int packed = (b0i & 0xff) | ((b1i & 0xff) << 8) |
                              ((b2i & 0xff) << 16) | ((b3i & 0xff) << 24);
  const int kt  = lane >> 3;            // (lane*4)/32
  const int k32 = (lane & 7) * 4;
  *(unsigned int*)(Wq + kt * 32768 + p * 32 + k32) = packed;

  if (lane < 8)  Wxk[p * 8 + lane] = (lane < I_) ? (f16)W_ih[row * I_ + lane] : (f16)0.f;
  if (lane == 8)  bsum_p[p]  = b_ih[row] + b_hh[row];
  if (lane == 9)  scd[p]     = mx * (1.f / 16129.f);   // mx/127^2
  if (lane == 10) invq127[p] = 16129.f / mx;           // 127^2/mx
}

// ---------------------------------------------------------------------------
// Kernel 1: distance + stable descending rank-sort + gather.
// xbuf: f16 [blk][rank(64)][bi(16)][8]; selfbuf: f32 [B][5].
// ---------------------------------------------------------------------------
__global__ void sort_gather(const float* __restrict__ state,
                            f16* __restrict__ xbuf,
                            float* __restrict__ selfbuf) {
  const int b = blockIdx.x;
  const int e = threadIdx.x;                 // 0..63, one wave
  const float* row = state + ((size_t)b * N_ + e) * 12;
  const float4* r4 = (const float4*)row;
  const float4 v0 = r4[0], v1 = r4[1], v2 = r4[2];
  float s[12];
  s[0]=v0.x; s[1]=v0.y; s[2]=v0.z;  s[3]=v0.w;
  s[4]=v1.x; s[5]=v1.y; s[6]=v1.z;  s[7]=v1.w;
  s[8]=v2.x; s[9]=v2.y; s[10]=v2.z; s[11]=v2.w;

  const float s5 = s[5], s6 = s[6];
  const float d = (s5 != 0.f && s6 != 0.f) ? sqrtf(s5 * s5 + s6 * s6) : INFINITY;

  __shared__ float dd[64];
  dd[e] = d;
  __syncthreads();

  int rank = 0;
  #pragma unroll
  for (int j = 0; j < 64; ++j) {
    const float dj = dd[j];
    rank += (dj > d || (dj == d && j < e)) ? 1 : 0;
  }

  f16* xo = xbuf + (((size_t)(b >> 4) * 64 + rank) * 16 + (b & 15)) * 8;
  #pragma unroll
  for (int f = 0; f < I_; ++f) xo[f] = (f16)s[SS_ + f];
  xo[7] = (f16)0.f;

  if (e == 0) {
    #pragma unroll
    for (int i = 0; i < SS_; ++i) selfbuf[b * SS_ + i] = s[i];
  }
}

// ---------------------------------------------------------------------------
// Kernel 2: i8 MFMA LSTM, register-resident W_hh. 256 blocks x 512 threads
// (8 waves = 2/SIMD, 1 block/CU), 16 batches/block. Wave w owns packed cols
// [128w,128w+128): ALL 8 k-tiles as i8 B-frags in VGPRs (128 regs, asm-
// pinned). h quantized i8 with per-block per-step dynamic scale sh
// (block max|h|). Gate = (i8acc)·(mx·sh/127^2); x@W_ih + bias folded in as
// round(F·127^2/(mx·sh)) per-ct (transient 4 f32 regs). All 64 steps of x
// staged in LDS once. Peak reg demand ~232 <= 256.
// LDS: xall 16384 + Bx 16384 + hq 5120 + wmax 32 = ~37.9 KB.
// ---------------------------------------------------------------------------
__global__ __attribute__((amdgpu_flat_work_group_size(512, 512)))
           __attribute__((amdgpu_waves_per_eu(2, 2)))
void lstm_kernel(
    const f16* __restrict__ xbuf,      // [256][64][16][8]
    const signed char* __restrict__ Wq,// [8][1024][32] i8
    const f16* __restrict__ Wxk,       // [1024][8]
    const float* __restrict__ bsum_p,  // [1024]
    const float* __restrict__ scd,     // [1024]  mx/127^2
    const float* __restrict__ invq127, // [1024]  127^2/mx
    float* __restrict__ hnbuf) {       // [B][256] fp32
  const int tid = threadIdx.x;
  const int l   = tid & 63;
  const int w   = tid >> 6;             // wave 0..7
  const int l15 = l & 15;
  const int lg  = l >> 4;               // 0..3
  const int b0  = blockIdx.x << 4;      // 16 batches per block

  __shared__ f16 xall[64 * 16 * 8];          // 16384 B  [t][bi][8]
  __shared__ f16 Bx_s[1024 * 8];             // 16384 B  [p][8]
  __shared__ signed char hq_s[8 * 16 * 40];  //  5120 B  [kt][b][40-pad]
  __shared__ float wmax_s[8];

  // --- one-time staging ---
  {
    const f16x8* sx = (const f16x8*)Wxk;
    f16x8* dx = (f16x8*)Bx_s;
    for (int i = tid; i < 1024; i += 512) dx[i] = sx[i];
    const f16x8* sa = (const f16x8*)(xbuf + (size_t)blockIdx.x * 8192);
    f16x8* da = (f16x8*)xall;
    for (int i = tid; i < 1024; i += 512) da[i] = sa[i];
    for (int i = tid; i < 1280; i += 512) ((int*)hq_s)[i] = 0;
  }

  // --- per-lane column constants (8 cols: p = w*128 + ct*16 + l15) ---
  float biasv[8], scv[8], invv[8];
  #pragma unroll
  for (int ct = 0; ct < 8; ++ct) {
    const int p = w * 128 + ct * 16 + l15;
    biasv[ct] = bsum_p[p];
    scv[ct]   = scd[p];
    invv[ct]  = invq127[p];
  }

  // --- persistent i8 B fragments, all 8 k-tiles (128 VGPRs) ---
  const int qbase = (w * 128 + l15) * 32 + lg * 8;
  long Bq[8][8];
  #pragma unroll
  for (int kt = 0; kt < 8; ++kt)
    #pragma unroll
    for (int ct = 0; ct < 8; ++ct)
      Bq[kt][ct] = *(const long*)(Wq + kt * 32768 + ct * 512 + qbase);

  const int hrd = l15 * 40 + lg * 8;    // A-frag read base (+kt*640)

  float c_[2][4];
  #pragma unroll
  for (int uh = 0; uh < 2; ++uh)
    #pragma unroll
    for (int q = 0; q < 4; ++q) c_[uh][q] = 0.f;

  float sh_prev = 1.f, ish_prev = 1.f;

  __syncthreads();   // staging visible

  #pragma unroll 1
  for (int t = 0; t < 64; ++t) {
    // opaque zero defeats LICM on loop-invariant LDS reads
    int z = 0;
    asm volatile("" : "+v"(z));

    // anti-sink: keep the i8 weight fragments register-resident
    #pragma unroll
    for (int kt = 0; kt < 8; ++kt)
      #pragma unroll
      for (int ct = 0; ct < 8; ++ct)
        asm volatile("" : "+v"(Bq[kt][ct]));

    // x A-fragment: row=batch=l15, k=lg*8+j valid only for lg==0
    f16x8 ax = {(f16)0.f,(f16)0.f,(f16)0.f,(f16)0.f,
                (f16)0.f,(f16)0.f,(f16)0.f,(f16)0.f};
    if (lg == 0) ax = *(const f16x8*)&xall[(t * 16 + l15) * 8 + z];

    // per-ct: F = bias + x@W_ih (f16 MFMA), fold to i32 domain immediately
    i32x4 acc[8];
    #pragma unroll
    for (int ct = 0; ct < 8; ++ct) {
      f32x4 accF = (f32x4){biasv[ct], biasv[ct], biasv[ct], biasv[ct]};
      const f16x8 Bv = *(const f16x8*)(Bx_s + (w * 128 + ct * 16 + l15) * 8 + z);
      accF = __builtin_amdgcn_mfma_f32_16x16x32_f16(ax, Bv, accF, 0, 0, 0);
      const float iv = invv[ct] * ish_prev;   // 127^2/(mx*sh)
      #pragma unroll
      for (int e = 0; e < 4; ++e) acc[ct][e] = (int)rintf(accF[e] * iv);
    }

    // hq @ Wq : 64 i8 MFMAs, B from registers
    #pragma unroll
    for (int kt = 0; kt < 8; ++kt) {
      const long Af = *(const long*)&hq_s[kt * 640 + hrd];
      #pragma unroll
      for (int ct = 0; ct < 8; ++ct)
        acc[ct] = __builtin_amdgcn_mfma_i32_16x16x32_i8(Af, Bq[kt][ct], acc[ct], 0, 0, 0);
    }

    // epilogue in registers: dequant + gates + h, track block max|h|
    float sc2[8];
    #pragma unroll
    for (int ct = 0; ct < 8; ++ct) sc2[ct] = scv[ct] * sh_prev;  // mx*sh/127^2

    float hv[2][4];
    float mloc = 0.f;
    #pragma unroll
    for (int uh = 0; uh < 2; ++uh) {
      #pragma unroll
      for (int q = 0; q < 4; ++q) {
        const float gi = (float)acc[0 + uh][q] * sc2[0 + uh];
        const float gf = (float)acc[2 + uh][q] * sc2[2 + uh];
        const float gg = (float)acc[4 + uh][q] * sc2[4 + uh];
        const float go = (float)acc[6 + uh][q] * sc2[6 + uh];
        const float cn = sigm_(gf) * c_[uh][q] + sigm_(gi) * tanh_(gg);
        c_[uh][q] = cn;
        const float h = sigm_(go) * tanh_(cn);
        hv[uh][q] = h;
        mloc = fmaxf(mloc, fabsf(h));
      }
    }
    #pragma unroll
    for (int off = 32; off; off >>= 1)
      mloc = fmaxf(mloc, __shfl_xor(mloc, off));
    if (l == 0) wmax_s[w] = mloc;

    __syncthreads();   // hq reads done; wave maxes visible

    float sh = 1e-8f;
    #pragma unroll
    for (int j = 0; j < 8; ++j) sh = fmaxf(sh, wmax_s[j]);
    const float qs = 127.f / sh;

    // quantize h and publish; write hn at final step
    #pragma unroll
    for (int uh = 0; uh < 2; ++uh) {
      const int wbq = w * 640 + uh * 16 + l15;
      const int u   = w * 32 + uh * 16 + l15;
      #pragma unroll
      for (int q = 0; q < 4; ++q) {
        const int b = lg * 4 + q;
        hq_s[wbq + b * 40] = (signed char)(int)rintf(hv[uh][q] * qs);
        if (t == 63) hnbuf[(size_t)(b0 + b) * H_ + u] = hv[uh][q];
      }
    }
    sh_prev  = sh;
    ish_prev = __builtin_amdgcn_rcpf(sh);
    __syncthreads();   // hq writes visible
  }
}

// ---------------------------------------------------------------------------
// Kernel 3: fused MLP head. 256 blocks x 512 threads, 16 batches per block.
// Dynamic LDS: a0 16x264 + a1 16x512 + a2 16x512 = 82432 B.
// ---------------------------------------------------------------------------
__global__ __launch_bounds__(512) void mlp_kernel(
    const float* __restrict__ selfb, const float* __restrict__ hnbuf,
    const float* __restrict__ W1, const float* __restrict__ b1,
    const float* __restrict__ W2, const float* __restrict__ b2,
    const float* __restrict__ Wv, const float* __restrict__ bv,
    float* __restrict__ out) {
  const int tid = threadIdx.x;
  const int b0  = blockIdx.x << 4;      // 16 batches per block
  const int tb  = tid >> 7;             // 0..3 (batch group)
  const int tn  = tid & 127;            // float4 column group (N=512 -> 128)

  extern __shared__ char smem[];
  float* a0 = (float*)smem;                    // [16][264]
  float* a1 = (float*)(smem + 16896);          // [16][512]
  float* a2 = (float*)(smem + 16896 + 32768);  // [16][512]

  for (int i = tid; i < 16 * SS_; i += 512)
    a0[(i / SS_) * 264 + (i % SS_)] = selfb[b0 * SS_ + i];
  for (int i = tid; i < 16 * H_; i += 512)
    a0[(i >> 8) * 264 + SS_ + (i & 255)] = hnbuf[((size_t)b0 << 8) + i];
  __syncthreads();

  float4 acc[4];

  { // layer 1: K=261, N=512
    const float4* W14 = (const float4*)W1;
    const float4 bb = ((const float4*)b1)[tn];
    #pragma unroll
    for (int q = 0; q < 4; ++q) acc[q] = bb;
    for (int k = 0; k < SS_ + H_; ++k) {
      const float4 w0 = W14[k * 128 + tn];
      #pragma unroll
      for (int q = 0; q < 4; ++q)
        fma4(acc[q], a0[(tb * 4 + q) * 264 + k], w0);
    }
    #pragma unroll
    for (int q = 0; q < 4; ++q)
      *(float4*)&a1[(tb * 4 + q) * 512 + tn * 4] = relu4(acc[q]);
  }
  __syncthreads();

  { // layer 2: K=512, N=512
    const float4* W24 = (const float4*)W2;
    const float4 bb = ((const float4*)b2)[tn];
    #pragma unroll
    for (int q = 0; q < 4; ++q) acc[q] = bb;
    for (int k = 0; k < M1_; ++k) {
      const float4 w0 = W24[k * 128 + tn];
      #pragma unroll
      for (int q = 0; q < 4; ++q)
        fma4(acc[q], a1[(tb * 4 + q) * 512 + k], w0);
    }
    #pragma unroll
    for (int q = 0; q < 4; ++q)
      *(float4*)&a2[(tb * 4 + q) * 512 + tn * 4] = relu4(acc[q]);
  }
  __syncthreads();

  // layer 3: K=512, N=81
  for (int idx = tid; idx < 16 * A_; idx += 512) {
    const int bi = idx / A_;
    const int n  = idx - bi * A_;
    float sum = bv[n];
    for (int k = 0; k < M2_; ++k)
      sum = fmaf(a2[bi * 512 + k], Wv[k * A_ + n], sum);
    out[(size_t)(b0 + bi) * A_ + n] = sum;
  }
}

// ---------------------------------------------------------------------------
extern "C" void kernel_launch(void* const* d_in, const int* in_sizes, int n_in,
                              void* d_out, int out_size, void* d_ws, size_t ws_size,
                              hipStream_t stream) {
  const float* state = (const float*)d_in[0];
  const float* W_ih  = (const float*)d_in[1];
  const float* W_hh  = (const float*)d_in[2];
  const float* b_ih  = (const float*)d_in[3];
  const float* b_hh  = (const float*)d_in[4];
  const float* W1    = (const float*)d_in[5];
  const float* b1    = (const float*)d_in[6];
  const float* W2    = (const float*)d_in[7];
  const float* b2    = (const float*)d_in[8];
  const float* Wv    = (const float*)d_in[9];
  const float* bv    = (const float*)d_in[10];
  float* out = (float*)d_out;

  // workspace layout (bytes, 16B-aligned); total ~8.76 MB
  char* ws = (char*)d_ws;
  signed char* Wq = (signed char*)(ws);        // 8*1024*32 i8  = 262144 B
  f16*   Wxk     = (f16*)(ws + 262144);        // 1024*8 f16    = 16384 B
  float* bsum_p  = (float*)(ws + 278528);      // 1024 f32      = 4096 B
  float* scd     = (float*)(ws + 282624);      // 1024 f32      = 4096 B
  float* invq127 = (float*)(ws + 286720);      // 1024 f32      = 4096 B
  f16*   xbuf    = (f16*)(ws + 290816);        // 256*64*16*8 f16 = 4194304 B
  float* selfb   = (float*)(ws + 4485120);     // 4096*5 f32    = 81920 B
  float* hnbuf   = (float*)(ws + 4567040);     // 4096*256 f32  = 4194304 B

  pack_weights<<<dim3(64), dim3(1024), 0, stream>>>(W_ih, W_hh, b_ih, b_hh,
                                                    Wq, Wxk, bsum_p, scd,
                                                    invq127);
  sort_gather<<<dim3(B_), dim3(64), 0, stream>>>(state, xbuf, selfb);
  lstm_kernel<<<dim3(B_ / 16), dim3(512), 0, stream>>>(xbuf, Wq, Wxk, bsum_p,
                                                       scd, invq127, hnbuf);
  mlp_kernel<<<dim3(B_ / 16), dim3(512), 82432, stream>>>(selfb, hnbuf, W1, b1,
                                                          W2, b2, Wv, bv, out);
}